// Round 7
// baseline (94.759 us; speedup 1.0000x reference)
//
#include <hip/hip_runtime.h>

#define S_   96
#define B_   16
#define D_   512
#define HID_ 128
#define M_   (S_ * B_)     // 1536
#define KC_  4             // K-split chunks
#define KCH_ (D_ / KC_)    // 128 per chunk
#define CHF_ (2 * M_ * HID_)   // floats per chunk buffer (ha+hb)

// Own POD vector types only — no HIP vector classes (non-POD, poison unions).
typedef __attribute__((ext_vector_type(4))) float        f32x4_t;
typedef __attribute__((ext_vector_type(2))) float        f32x2_t;
typedef __attribute__((ext_vector_type(4))) unsigned int u32x4_t;
typedef __attribute__((ext_vector_type(8))) short        short8;   // bf16x8 MFMA frag

// Split 8 f32 into hi/lo truncated-bf16 fragments (3-MFMA f32-grade emulation).
static __device__ __forceinline__ void split8(f32x4_t a, f32x4_t b,
                                              short8& hi, short8& lo) {
    float f[8];
    #pragma unroll
    for (int j = 0; j < 4; ++j) { f[j] = a[j]; f[4 + j] = b[j]; }
    unsigned int hb[8], lb[8];
    #pragma unroll
    for (int j = 0; j < 8; ++j) {
        unsigned int u = __float_as_uint(f[j]);
        float hf = __uint_as_float(u & 0xffff0000u);
        hb[j] = u >> 16;
        lb[j] = __float_as_uint(f[j] - hf) >> 16;
    }
    union { u32x4_t u; short8 s; } H, L;
    #pragma unroll
    for (int j = 0; j < 4; ++j) {
        H.u[j] = hb[2 * j] | (hb[2 * j + 1] << 16);
        L.u[j] = lb[2 * j] | (lb[2 * j + 1] << 16);
    }
    hi = H.s; lo = L.s;
}

// Stage 1 (MFMA, split-bf16, K-split x4):
//   ws[kc][z][m][h] = sum_{d in chunk kc} x[m][d]*W1[h][z*512+d]  (+b1 at kc=0,z=0)
// grid (48, 8, 4), block 256 = 4 waves; wave = one 16x16 tile over K=128.
// 6144 waves = 24 waves/CU -> latency hiding (was 6/CU at K=512).
__global__ __launch_bounds__(256) void stage1_mfma(
    const float* __restrict__ emb,
    const float* __restrict__ embc,
    const float* __restrict__ W1,
    const float* __restrict__ b1,
    float* __restrict__ ws)
{
    const int wave = threadIdx.x >> 6;
    const int lane = threadIdx.x & 63;
    const int gm = blockIdx.x * 64 + wave * 16;   // [0,3072); 1536 boundary block-aligned
    const int z  = (gm >= M_) ? 1 : 0;
    const int m0 = gm - z * M_;
    const int n0 = blockIdx.y * 16;
    const int kc = blockIdx.z;

    const int rsel = lane & 15;
    const int kq   = (lane >> 4) * 8;
    const float* xr = (z ? embc : emb) + (m0 + rsel) * D_ + kc * KCH_ + kq;
    const float* wr = W1 + (n0 + rsel) * (2 * D_) + z * D_ + kc * KCH_ + kq;

    f32x4_t acc = {0.f, 0.f, 0.f, 0.f};
    #pragma unroll
    for (int k = 0; k < KCH_; k += 32) {
        f32x4_t xa = *(const f32x4_t*)(xr + k);
        f32x4_t xb = *(const f32x4_t*)(xr + k + 4);
        f32x4_t wa = *(const f32x4_t*)(wr + k);
        f32x4_t wb = *(const f32x4_t*)(wr + k + 4);
        short8 xhi, xlo, whi, wlo;
        split8(xa, xb, xhi, xlo);
        split8(wa, wb, whi, wlo);
        acc = __builtin_amdgcn_mfma_f32_16x16x32_bf16(xhi, whi, acc, 0, 0, 0);
        acc = __builtin_amdgcn_mfma_f32_16x16x32_bf16(xhi, wlo, acc, 0, 0, 0);
        acc = __builtin_amdgcn_mfma_f32_16x16x32_bf16(xlo, whi, acc, 0, 0, 0);
    }

    // C/D layout: col(h)=lane&15, row(m)=(lane>>4)*4+reg  [m89/m91 HW-verified]
    const int h = n0 + rsel;
    const float bias = (z == 0 && kc == 0) ? b1[h] : 0.f;
    const int mrow = m0 + (lane >> 4) * 4;
    float* dst = ws + (size_t)kc * CHF_ + (size_t)z * (M_ * HID_);
    #pragma unroll
    for (int r = 0; r < 4; ++r) {
        dst[(mrow + r) * HID_ + h] = acc[r] + bias;
    }
}

// Stage 2: out[i,j,b,c] = relu(ha[i,b,:]+hb[j,b,:]) . W2[c,:] + b2[c]
// grid (6, 6, 16), block 256: one (i,j) pair per thread. Sums 4 K-chunk partials
// during the LDS-staging load phase.
__global__ __launch_bounds__(256) void stage2(
    const float* __restrict__ ws,
    const float* __restrict__ W2,
    const float* __restrict__ b2,
    float* __restrict__ out)
{
    __shared__ float ha_s[16 * 132];   // stride 132: tj-strided reads 2-way alias (free)
    __shared__ float hb_s[16 * 132];
    __shared__ float w2_s[2 * HID_];

    const int t  = threadIdx.x;
    const int i0 = blockIdx.x * 16;
    const int j0 = blockIdx.y * 16;
    const int b  = blockIdx.z;

    {
        const int r = t >> 4;
        const int c = (t & 15) * 8;
        const float* pHa = ws + ((i0 + r) * B_ + b) * HID_ + c;              // kc=0, z=0
        const float* pHb = ws + (M_ * HID_) + ((j0 + r) * B_ + b) * HID_ + c; // kc=0, z=1
        f32x4_t a0 = *(const f32x4_t*)pHa,       a1 = *(const f32x4_t*)(pHa + 4);
        f32x4_t b0 = *(const f32x4_t*)pHb,       b1v = *(const f32x4_t*)(pHb + 4);
        #pragma unroll
        for (int kc = 1; kc < KC_; ++kc) {
            const float* qa = pHa + (size_t)kc * CHF_;
            const float* qb = pHb + (size_t)kc * CHF_;
            a0  += *(const f32x4_t*)qa;       a1  += *(const f32x4_t*)(qa + 4);
            b0  += *(const f32x4_t*)qb;       b1v += *(const f32x4_t*)(qb + 4);
        }
        *(f32x4_t*)&ha_s[r * 132 + c]     = a0;
        *(f32x4_t*)&ha_s[r * 132 + c + 4] = a1;
        *(f32x4_t*)&hb_s[r * 132 + c]     = b0;
        *(f32x4_t*)&hb_s[r * 132 + c + 4] = b1v;
        w2_s[t] = W2[t];                 // W2 is (2,128) row-major, 256 elems
    }
    __syncthreads();

    const int ti = t >> 4, tj = t & 15;
    const float* pa = &ha_s[ti * 132];
    const float* pb = &hb_s[tj * 132];
    float acc0 = 0.f, acc1 = 0.f;
    #pragma unroll
    for (int h = 0; h < HID_; h += 4) {
        f32x4_t av = *(const f32x4_t*)(pa + h);
        f32x4_t bv = *(const f32x4_t*)(pb + h);
        f32x4_t w0 = *(const f32x4_t*)&w2_s[h];
        f32x4_t w1 = *(const f32x4_t*)&w2_s[HID_ + h];
        #pragma unroll
        for (int q = 0; q < 4; ++q) {
            float v = fmaxf(av[q] + bv[q], 0.f);
            acc0 = fmaf(v, w0[q], acc0);
            acc1 = fmaf(v, w1[q], acc1);
        }
    }

    const int i = i0 + ti, j = j0 + tj;
    const int idx = ((i * S_ + j) * B_ + b) * 2;
    f32x2_t o = { acc0 + b2[0], acc1 + b2[1] };
    *(f32x2_t*)(out + idx) = o;          // idx even -> 8B aligned
}

// Fallback if ws is unusable: recompute ha/hb tiles per block. Correctness-only.
__global__ __launch_bounds__(256) void fused_fallback(
    const float* __restrict__ emb,
    const float* __restrict__ embc,
    const float* __restrict__ W1,
    const float* __restrict__ b1,
    const float* __restrict__ W2,
    const float* __restrict__ b2,
    float* __restrict__ out)
{
    __shared__ float ha_s[16 * 132];
    __shared__ float hb_s[16 * 132];
    __shared__ float w2_s[2 * HID_];

    const int t  = threadIdx.x;
    const int i0 = blockIdx.x * 16;
    const int j0 = blockIdx.y * 16;
    const int b  = blockIdx.z;

    w2_s[t] = W2[t];

    for (int o = t; o < 4096; o += 256) {
        const int side = o >> 11;
        const int mi   = (o >> 7) & 15;
        const int h    = o & 127;
        const int srow = ((side ? j0 : i0) + mi) * B_ + b;
        const float* x = (side ? embc : emb) + srow * D_;
        const float* w = W1 + h * (2 * D_) + side * D_;
        float s = side ? 0.f : b1[h];
        for (int d = 0; d < D_; d += 4) {
            f32x4_t xv = *(const f32x4_t*)(x + d);
            f32x4_t wv = *(const f32x4_t*)(w + d);
            s = fmaf(xv[0], wv[0], s);
            s = fmaf(xv[1], wv[1], s);
            s = fmaf(xv[2], wv[2], s);
            s = fmaf(xv[3], wv[3], s);
        }
        (side ? hb_s : ha_s)[mi * 132 + h] = s;
    }
    __syncthreads();

    const int ti = t >> 4, tj = t & 15;
    const float* pa = &ha_s[ti * 132];
    const float* pb = &hb_s[tj * 132];
    float acc0 = 0.f, acc1 = 0.f;
    #pragma unroll
    for (int h = 0; h < HID_; h += 4) {
        f32x4_t av = *(const f32x4_t*)(pa + h);
        f32x4_t bv = *(const f32x4_t*)(pb + h);
        f32x4_t w0 = *(const f32x4_t*)&w2_s[h];
        f32x4_t w1 = *(const f32x4_t*)&w2_s[HID_ + h];
        #pragma unroll
        for (int q = 0; q < 4; ++q) {
            float v = fmaxf(av[q] + bv[q], 0.f);
            acc0 = fmaf(v, w0[q], acc0);
            acc1 = fmaf(v, w1[q], acc1);
        }
    }
    const int i = i0 + ti, j = j0 + tj;
    const int idx = ((i * S_ + j) * B_ + b) * 2;
    f32x2_t ov = { acc0 + b2[0], acc1 + b2[1] };
    *(f32x2_t*)(out + idx) = ov;
}

extern "C" void kernel_launch(void* const* d_in, const int* in_sizes, int n_in,
                              void* d_out, int out_size, void* d_ws, size_t ws_size,
                              hipStream_t stream) {
    const float* emb  = (const float*)d_in[0];
    // d_in[1] = umask (unused), d_in[2] = qmask (unused)
    const float* embc = (const float*)d_in[3];
    const float* W1   = (const float*)d_in[4];
    const float* b1   = (const float*)d_in[5];
    const float* W2   = (const float*)d_in[6];
    const float* b2   = (const float*)d_in[7];
    float* out = (float*)d_out;

    const size_t need = (size_t)KC_ * CHF_ * sizeof(float);  // 6.29 MB
    if (d_ws != nullptr && ws_size >= need) {
        float* ws = (float*)d_ws;   // ws[kc][z][m][h]
        stage1_mfma<<<dim3(48, 8, KC_), 256, 0, stream>>>(emb, embc, W1, b1, ws);
        stage2<<<dim3(6, 6, 16), 256, 0, stream>>>(ws, W2, b2, out);
    } else {
        fused_fallback<<<dim3(6, 6, 16), 256, 0, stream>>>(emb, embc, W1, b1, W2, b2, out);
    }
}

// Round 8
// 88.209 us; speedup vs baseline: 1.0742x; 1.0742x over previous
//
#include <hip/hip_runtime.h>

#define S_   96
#define B_   16
#define D_   512
#define HID_ 128
#define M_   (S_ * B_)     // 1536
#define KC_  4             // K-split chunks
#define KCH_ (D_ / KC_)    // 128 per chunk
#define CHF_ (2 * M_ * HID_)   // floats per chunk buffer (ha+hb)

// Own POD vector types only — no HIP vector classes (non-POD, poison unions).
typedef __attribute__((ext_vector_type(4))) float        f32x4_t;
typedef __attribute__((ext_vector_type(2))) float        f32x2_t;
typedef __attribute__((ext_vector_type(4))) unsigned int u32x4_t;
typedef __attribute__((ext_vector_type(8))) short        short8;   // bf16x8 MFMA frag

// Split 8 f32 into hi/lo truncated-bf16 fragments (3-MFMA f32-grade emulation).
static __device__ __forceinline__ void split8(f32x4_t a, f32x4_t b,
                                              short8& hi, short8& lo) {
    float f[8];
    #pragma unroll
    for (int j = 0; j < 4; ++j) { f[j] = a[j]; f[4 + j] = b[j]; }
    unsigned int hb[8], lb[8];
    #pragma unroll
    for (int j = 0; j < 8; ++j) {
        unsigned int u = __float_as_uint(f[j]);
        float hf = __uint_as_float(u & 0xffff0000u);
        hb[j] = u >> 16;
        lb[j] = __float_as_uint(f[j] - hf) >> 16;
    }
    union { u32x4_t u; short8 s; } H, L;
    #pragma unroll
    for (int j = 0; j < 4; ++j) {
        H.u[j] = hb[2 * j] | (hb[2 * j + 1] << 16);
        L.u[j] = lb[2 * j] | (lb[2 * j + 1] << 16);
    }
    hi = H.s; lo = L.s;
}

// Stage 1 (MFMA, split-bf16, LDS-staged 64x64 tiles, K-split x4):
//   ws[kc][z][m][h] = sum_{d in chunk kc} x[m][d]*W1[h][z*512+d]  (+b1 at kc=0,z=0)
// grid (48 m-blocks, 2 h-halves, 4 kc), block 256 = 4 waves (2x2), wave = 32x32 C.
// Global loads are fully coalesced into LDS; MFMA fragments come from ds_read_b128.
__global__ __launch_bounds__(256) void stage1_mfma(
    const float* __restrict__ emb,
    const float* __restrict__ embc,
    const float* __restrict__ W1,
    const float* __restrict__ b1,
    float* __restrict__ ws)
{
    __shared__ float x_s[64 * 132];   // 64 m-rows x 128 k (+4 pad: 2-way alias max = free)
    __shared__ float w_s[64 * 132];   // 64 h-rows x 128 k

    const int t    = threadIdx.x;
    const int wave = t >> 6;
    const int lane = t & 63;
    const int bx   = blockIdx.x;          // m-block (64 rows); z boundary at bx=24
    const int h0   = blockIdx.y * 64;     // h-half
    const int kc   = blockIdx.z;          // k-chunk

    const int z    = (bx >= 24) ? 1 : 0;
    const int mloc = bx * 64 - z * M_;    // local row start in emb/embc

    const float* xbase = (z ? embc : emb) + (size_t)mloc * D_ + kc * KCH_;
    const float* wbase = W1 + (size_t)h0 * (2 * D_) + z * D_ + kc * KCH_;

    // Coalesced staging: 2048 f32x4 per tile, 8 per thread.
    #pragma unroll
    for (int rep = 0; rep < 8; ++rep) {
        const int idx = rep * 256 + t;
        const int row = idx >> 5;          // 0..63
        const int c4  = (idx & 31) * 4;    // 0..124
        *(f32x4_t*)&x_s[row * 132 + c4] = *(const f32x4_t*)(xbase + row * D_ + c4);
        *(f32x4_t*)&w_s[row * 132 + c4] = *(const f32x4_t*)(wbase + row * (2 * D_) + c4);
    }
    __syncthreads();

    const int rsel = lane & 15;
    const int kq   = (lane >> 4) * 8;
    const int wm   = (wave & 1) * 32;     // wave's m offset in tile
    const int wh   = (wave >> 1) * 32;    // wave's h offset in tile

    f32x4_t acc[2][2] = {{{0.f,0.f,0.f,0.f},{0.f,0.f,0.f,0.f}},
                         {{0.f,0.f,0.f,0.f},{0.f,0.f,0.f,0.f}}};
    #pragma unroll
    for (int kk = 0; kk < KCH_; kk += 32) {
        short8 ahi[2], alo[2], bhi[2], blo[2];
        #pragma unroll
        for (int ms = 0; ms < 2; ++ms) {
            const float* p = &x_s[(wm + ms * 16 + rsel) * 132 + kk + kq];
            split8(*(const f32x4_t*)p, *(const f32x4_t*)(p + 4), ahi[ms], alo[ms]);
        }
        #pragma unroll
        for (int hs = 0; hs < 2; ++hs) {
            const float* p = &w_s[(wh + hs * 16 + rsel) * 132 + kk + kq];
            split8(*(const f32x4_t*)p, *(const f32x4_t*)(p + 4), bhi[hs], blo[hs]);
        }
        #pragma unroll
        for (int ms = 0; ms < 2; ++ms)
            #pragma unroll
            for (int hs = 0; hs < 2; ++hs) {
                acc[ms][hs] = __builtin_amdgcn_mfma_f32_16x16x32_bf16(ahi[ms], bhi[hs], acc[ms][hs], 0, 0, 0);
                acc[ms][hs] = __builtin_amdgcn_mfma_f32_16x16x32_bf16(ahi[ms], blo[hs], acc[ms][hs], 0, 0, 0);
                acc[ms][hs] = __builtin_amdgcn_mfma_f32_16x16x32_bf16(alo[ms], bhi[hs], acc[ms][hs], 0, 0, 0);
            }
    }

    // C/D layout: col(h)=lane&15, row(m)=(lane>>4)*4+reg  [m89/m91 HW-verified]
    float* dst = ws + (size_t)kc * CHF_ + (size_t)z * (M_ * HID_);
    const int mrow_base = mloc + wm + (lane >> 4) * 4;
    #pragma unroll
    for (int ms = 0; ms < 2; ++ms) {
        #pragma unroll
        for (int hs = 0; hs < 2; ++hs) {
            const int h = h0 + wh + hs * 16 + rsel;
            const float bias = (z == 0 && kc == 0) ? b1[h] : 0.f;
            #pragma unroll
            for (int r = 0; r < 4; ++r) {
                dst[(mrow_base + ms * 16 + r) * HID_ + h] = acc[ms][hs][r] + bias;
            }
        }
    }
}

// Stage 2: out[i,j,b,c] = relu(ha[i,b,:]+hb[j,b,:]) . W2[c,:] + b2[c]
// grid (6, 6, 16), block 256: one (i,j) pair per thread. Sums 4 K-chunk partials
// during the LDS-staging load phase.
__global__ __launch_bounds__(256) void stage2(
    const float* __restrict__ ws,
    const float* __restrict__ W2,
    const float* __restrict__ b2,
    float* __restrict__ out)
{
    __shared__ float ha_s[16 * 132];
    __shared__ float hb_s[16 * 132];
    __shared__ float w2_s[2 * HID_];

    const int t  = threadIdx.x;
    const int i0 = blockIdx.x * 16;
    const int j0 = blockIdx.y * 16;
    const int b  = blockIdx.z;

    {
        const int r = t >> 4;
        const int c = (t & 15) * 8;
        const float* pHa = ws + ((i0 + r) * B_ + b) * HID_ + c;               // kc=0, z=0
        const float* pHb = ws + (M_ * HID_) + ((j0 + r) * B_ + b) * HID_ + c; // kc=0, z=1
        f32x4_t a0 = *(const f32x4_t*)pHa,  a1  = *(const f32x4_t*)(pHa + 4);
        f32x4_t b0 = *(const f32x4_t*)pHb,  b1v = *(const f32x4_t*)(pHb + 4);
        #pragma unroll
        for (int kc = 1; kc < KC_; ++kc) {
            const float* qa = pHa + (size_t)kc * CHF_;
            const float* qb = pHb + (size_t)kc * CHF_;
            a0  += *(const f32x4_t*)qa;   a1  += *(const f32x4_t*)(qa + 4);
            b0  += *(const f32x4_t*)qb;   b1v += *(const f32x4_t*)(qb + 4);
        }
        *(f32x4_t*)&ha_s[r * 132 + c]     = a0;
        *(f32x4_t*)&ha_s[r * 132 + c + 4] = a1;
        *(f32x4_t*)&hb_s[r * 132 + c]     = b0;
        *(f32x4_t*)&hb_s[r * 132 + c + 4] = b1v;
        w2_s[t] = W2[t];
    }
    __syncthreads();

    const int ti = t >> 4, tj = t & 15;
    const float* pa = &ha_s[ti * 132];
    const float* pb = &hb_s[tj * 132];
    float acc0 = 0.f, acc1 = 0.f;
    #pragma unroll
    for (int h = 0; h < HID_; h += 4) {
        f32x4_t av = *(const f32x4_t*)(pa + h);
        f32x4_t bv = *(const f32x4_t*)(pb + h);
        f32x4_t w0 = *(const f32x4_t*)&w2_s[h];
        f32x4_t w1 = *(const f32x4_t*)&w2_s[HID_ + h];
        #pragma unroll
        for (int q = 0; q < 4; ++q) {
            float v = fmaxf(av[q] + bv[q], 0.f);
            acc0 = fmaf(v, w0[q], acc0);
            acc1 = fmaf(v, w1[q], acc1);
        }
    }

    const int i = i0 + ti, j = j0 + tj;
    const int idx = ((i * S_ + j) * B_ + b) * 2;
    f32x2_t o = { acc0 + b2[0], acc1 + b2[1] };
    *(f32x2_t*)(out + idx) = o;
}

// Fallback if ws is unusable: recompute ha/hb tiles per block. Correctness-only.
__global__ __launch_bounds__(256) void fused_fallback(
    const float* __restrict__ emb,
    const float* __restrict__ embc,
    const float* __restrict__ W1,
    const float* __restrict__ b1,
    const float* __restrict__ W2,
    const float* __restrict__ b2,
    float* __restrict__ out)
{
    __shared__ float ha_s[16 * 132];
    __shared__ float hb_s[16 * 132];
    __shared__ float w2_s[2 * HID_];

    const int t  = threadIdx.x;
    const int i0 = blockIdx.x * 16;
    const int j0 = blockIdx.y * 16;
    const int b  = blockIdx.z;

    w2_s[t] = W2[t];

    for (int o = t; o < 4096; o += 256) {
        const int side = o >> 11;
        const int mi   = (o >> 7) & 15;
        const int h    = o & 127;
        const int srow = ((side ? j0 : i0) + mi) * B_ + b;
        const float* x = (side ? embc : emb) + srow * D_;
        const float* w = W1 + h * (2 * D_) + side * D_;
        float s = side ? 0.f : b1[h];
        for (int d = 0; d < D_; d += 4) {
            f32x4_t xv = *(const f32x4_t*)(x + d);
            f32x4_t wv = *(const f32x4_t*)(w + d);
            s = fmaf(xv[0], wv[0], s);
            s = fmaf(xv[1], wv[1], s);
            s = fmaf(xv[2], wv[2], s);
            s = fmaf(xv[3], wv[3], s);
        }
        (side ? hb_s : ha_s)[mi * 132 + h] = s;
    }
    __syncthreads();

    const int ti = t >> 4, tj = t & 15;
    const float* pa = &ha_s[ti * 132];
    const float* pb = &hb_s[tj * 132];
    float acc0 = 0.f, acc1 = 0.f;
    #pragma unroll
    for (int h = 0; h < HID_; h += 4) {
        f32x4_t av = *(const f32x4_t*)(pa + h);
        f32x4_t bv = *(const f32x4_t*)(pb + h);
        f32x4_t w0 = *(const f32x4_t*)&w2_s[h];
        f32x4_t w1 = *(const f32x4_t*)&w2_s[HID_ + h];
        #pragma unroll
        for (int q = 0; q < 4; ++q) {
            float v = fmaxf(av[q] + bv[q], 0.f);
            acc0 = fmaf(v, w0[q], acc0);
            acc1 = fmaf(v, w1[q], acc1);
        }
    }
    const int i = i0 + ti, j = j0 + tj;
    const int idx = ((i * S_ + j) * B_ + b) * 2;
    f32x2_t ov = { acc0 + b2[0], acc1 + b2[1] };
    *(f32x2_t*)(out + idx) = ov;
}

extern "C" void kernel_launch(void* const* d_in, const int* in_sizes, int n_in,
                              void* d_out, int out_size, void* d_ws, size_t ws_size,
                              hipStream_t stream) {
    const float* emb  = (const float*)d_in[0];
    // d_in[1] = umask (unused), d_in[2] = qmask (unused)
    const float* embc = (const float*)d_in[3];
    const float* W1   = (const float*)d_in[4];
    const float* b1   = (const float*)d_in[5];
    const float* W2   = (const float*)d_in[6];
    const float* b2   = (const float*)d_in[7];
    float* out = (float*)d_out;

    const size_t need = (size_t)KC_ * CHF_ * sizeof(float);  // 6.29 MB
    if (d_ws != nullptr && ws_size >= need) {
        float* ws = (float*)d_ws;   // ws[kc][z][m][h]
        stage1_mfma<<<dim3(48, 2, KC_), 256, 0, stream>>>(emb, embc, W1, b1, ws);
        stage2<<<dim3(6, 6, 16), 256, 0, stream>>>(ws, W2, b2, out);
    } else {
        fused_fallback<<<dim3(6, 6, 16), 256, 0, stream>>>(emb, embc, W1, b1, W2, b2, out);
    }
}

// Round 9
// 85.375 us; speedup vs baseline: 1.1099x; 1.0332x over previous
//
#include <hip/hip_runtime.h>

#define S_   96
#define B_   16
#define D_   512
#define HID_ 128
#define M_   (S_ * B_)     // 1536
#define KC_  4             // K-split chunks
#define KCH_ (D_ / KC_)    // 128 per chunk
#define CHF_ (2 * M_ * HID_)   // floats per chunk buffer (ha+hb)
#define LSTR_ 136          // LDS row stride in halfwords (272 B): uniform bank quads

// Own POD vector types only — no HIP vector classes (non-POD, poison unions).
typedef __attribute__((ext_vector_type(4))) float        f32x4_t;
typedef __attribute__((ext_vector_type(2))) float        f32x2_t;
typedef __attribute__((ext_vector_type(4))) unsigned int u32x4_t;
typedef __attribute__((ext_vector_type(8))) short        short8;   // bf16x8 MFMA frag

// Split 8 f32 into hi/lo truncated-bf16 fragments (3-MFMA f32-grade emulation).
static __device__ __forceinline__ void split8(f32x4_t a, f32x4_t b,
                                              short8& hi, short8& lo) {
    float f[8];
    #pragma unroll
    for (int j = 0; j < 4; ++j) { f[j] = a[j]; f[4 + j] = b[j]; }
    unsigned int hb[8], lb[8];
    #pragma unroll
    for (int j = 0; j < 8; ++j) {
        unsigned int u = __float_as_uint(f[j]);
        float hf = __uint_as_float(u & 0xffff0000u);
        hb[j] = u >> 16;
        lb[j] = __float_as_uint(f[j] - hf) >> 16;
    }
    union { u32x4_t u; short8 s; } H, L;
    #pragma unroll
    for (int j = 0; j < 4; ++j) {
        H.u[j] = hb[2 * j] | (hb[2 * j + 1] << 16);
        L.u[j] = lb[2 * j] | (lb[2 * j + 1] << 16);
    }
    hi = H.s; lo = L.s;
}

// Stage 1 (MFMA, pre-split hi/lo bf16 LDS tiles, K-split x4):
//   ws[kc][z][m][h] = sum_{d in chunk kc} x[m][d]*W1[h][z*512+d]  (+b1 at kc=0,z=0)
// grid (48 m-blocks, 2 h-halves, 4 kc), block 256 = 4 waves (2x2), wave = 32x32 C.
// Staging splits each f32 element ONCE; MFMA loop is pure ds_read_b128 + MFMA.
__global__ __launch_bounds__(256) void stage1_mfma(
    const float* __restrict__ emb,
    const float* __restrict__ embc,
    const float* __restrict__ W1,
    const float* __restrict__ b1,
    float* __restrict__ ws)
{
    __shared__ short x_hi[64 * LSTR_];   // 64 rows x 128 k bf16-hi (17 KB each)
    __shared__ short x_lo[64 * LSTR_];
    __shared__ short w_hi[64 * LSTR_];
    __shared__ short w_lo[64 * LSTR_];

    const int t    = threadIdx.x;
    const int wave = t >> 6;
    const int lane = t & 63;
    const int bx   = blockIdx.x;          // m-block (64 rows); z boundary at bx=24
    const int h0   = blockIdx.y * 64;     // h-half
    const int kc   = blockIdx.z;          // k-chunk

    const int z    = (bx >= 24) ? 1 : 0;
    const int mloc = bx * 64 - z * M_;    // local row start in emb/embc

    const float* xbase = (z ? embc : emb) + (size_t)mloc * D_ + kc * KCH_;
    const float* wbase = W1 + (size_t)h0 * (2 * D_) + z * D_ + kc * KCH_;

    // Staging + one-time split: 1024 k-groups per tile, 4 per thread per tile.
    #pragma unroll
    for (int rep = 0; rep < 4; ++rep) {
        const int idx = rep * 256 + t;    // [0,1024)
        const int row = idx >> 4;         // 0..63
        const int g   = idx & 15;         // k-group 0..15 (8 floats)
        short8 hi, lo;
        const float* px = xbase + row * D_ + g * 8;
        split8(*(const f32x4_t*)px, *(const f32x4_t*)(px + 4), hi, lo);
        *(short8*)&x_hi[row * LSTR_ + g * 8] = hi;
        *(short8*)&x_lo[row * LSTR_ + g * 8] = lo;
        const float* pw = wbase + row * (2 * D_) + g * 8;
        split8(*(const f32x4_t*)pw, *(const f32x4_t*)(pw + 4), hi, lo);
        *(short8*)&w_hi[row * LSTR_ + g * 8] = hi;
        *(short8*)&w_lo[row * LSTR_ + g * 8] = lo;
    }
    __syncthreads();

    const int rsel = lane & 15;
    const int gq   = lane >> 4;           // 0..3
    const int wm   = (wave & 1) * 32;     // wave's m offset in tile
    const int wh   = (wave >> 1) * 32;    // wave's h offset in tile

    f32x4_t acc[2][2] = {{{0.f,0.f,0.f,0.f},{0.f,0.f,0.f,0.f}},
                         {{0.f,0.f,0.f,0.f},{0.f,0.f,0.f,0.f}}};
    #pragma unroll
    for (int kk = 0; kk < KCH_; kk += 32) {
        const int goff = (kk >> 3) + gq;  // k-group for this lane
        short8 ahi[2], alo[2], bhi[2], blo[2];
        #pragma unroll
        for (int ms = 0; ms < 2; ++ms) {
            const int o = (wm + ms * 16 + rsel) * LSTR_ + goff * 8;
            ahi[ms] = *(const short8*)&x_hi[o];
            alo[ms] = *(const short8*)&x_lo[o];
        }
        #pragma unroll
        for (int hs = 0; hs < 2; ++hs) {
            const int o = (wh + hs * 16 + rsel) * LSTR_ + goff * 8;
            bhi[hs] = *(const short8*)&w_hi[o];
            blo[hs] = *(const short8*)&w_lo[o];
        }
        #pragma unroll
        for (int ms = 0; ms < 2; ++ms)
            #pragma unroll
            for (int hs = 0; hs < 2; ++hs) {
                acc[ms][hs] = __builtin_amdgcn_mfma_f32_16x16x32_bf16(ahi[ms], bhi[hs], acc[ms][hs], 0, 0, 0);
                acc[ms][hs] = __builtin_amdgcn_mfma_f32_16x16x32_bf16(ahi[ms], blo[hs], acc[ms][hs], 0, 0, 0);
                acc[ms][hs] = __builtin_amdgcn_mfma_f32_16x16x32_bf16(alo[ms], bhi[hs], acc[ms][hs], 0, 0, 0);
            }
    }

    // C/D layout: col(h)=lane&15, row(m)=(lane>>4)*4+reg  [m89/m91 HW-verified]
    float* dst = ws + (size_t)kc * CHF_ + (size_t)z * (M_ * HID_);
    const int mrow_base = mloc + wm + (lane >> 4) * 4;
    #pragma unroll
    for (int ms = 0; ms < 2; ++ms) {
        #pragma unroll
        for (int hs = 0; hs < 2; ++hs) {
            const int h = h0 + wh + hs * 16 + rsel;
            const float bias = (z == 0 && kc == 0) ? b1[h] : 0.f;
            #pragma unroll
            for (int r = 0; r < 4; ++r) {
                dst[(mrow_base + ms * 16 + r) * HID_ + h] = acc[ms][hs][r] + bias;
            }
        }
    }
}

// Stage 2: out[i,j,b,c] = relu(ha[i,b,:]+hb[j,b,:]) . W2[c,:] + b2[c]
// grid (6, 6, 16), block 256: one (i,j) pair per thread. W2/b2 via scalar loads
// (block-uniform addresses), halving per-thread LDS reads.
__global__ __launch_bounds__(256) void stage2(
    const float* __restrict__ ws,
    const float* __restrict__ W2,
    const float* __restrict__ b2,
    float* __restrict__ out)
{
    __shared__ float ha_s[16 * 132];
    __shared__ float hb_s[16 * 132];

    const int t  = threadIdx.x;
    const int i0 = blockIdx.x * 16;
    const int j0 = blockIdx.y * 16;
    const int b  = blockIdx.z;

    {
        const int r = t >> 4;
        const int c = (t & 15) * 8;
        const float* pHa = ws + ((i0 + r) * B_ + b) * HID_ + c;               // kc=0, z=0
        const float* pHb = ws + (M_ * HID_) + ((j0 + r) * B_ + b) * HID_ + c; // kc=0, z=1
        f32x4_t a0 = *(const f32x4_t*)pHa,  a1  = *(const f32x4_t*)(pHa + 4);
        f32x4_t b0 = *(const f32x4_t*)pHb,  b1v = *(const f32x4_t*)(pHb + 4);
        #pragma unroll
        for (int kc = 1; kc < KC_; ++kc) {
            const float* qa = pHa + (size_t)kc * CHF_;
            const float* qb = pHb + (size_t)kc * CHF_;
            a0  += *(const f32x4_t*)qa;   a1  += *(const f32x4_t*)(qa + 4);
            b0  += *(const f32x4_t*)qb;   b1v += *(const f32x4_t*)(qb + 4);
        }
        *(f32x4_t*)&ha_s[r * 132 + c]     = a0;
        *(f32x4_t*)&ha_s[r * 132 + c + 4] = a1;
        *(f32x4_t*)&hb_s[r * 132 + c]     = b0;
        *(f32x4_t*)&hb_s[r * 132 + c + 4] = b1v;
    }
    __syncthreads();

    const int ti = t >> 4, tj = t & 15;
    const float* pa = &ha_s[ti * 132];
    const float* pb = &hb_s[tj * 132];
    float acc0 = 0.f, acc1 = 0.f;
    #pragma unroll
    for (int h = 0; h < HID_; h += 4) {
        f32x4_t av = *(const f32x4_t*)(pa + h);
        f32x4_t bv = *(const f32x4_t*)(pb + h);
        f32x4_t w0 = *(const f32x4_t*)(W2 + h);          // uniform -> s_load
        f32x4_t w1 = *(const f32x4_t*)(W2 + HID_ + h);   // uniform -> s_load
        #pragma unroll
        for (int q = 0; q < 4; ++q) {
            float v = fmaxf(av[q] + bv[q], 0.f);
            acc0 = fmaf(v, w0[q], acc0);
            acc1 = fmaf(v, w1[q], acc1);
        }
    }

    const int i = i0 + ti, j = j0 + tj;
    const int idx = ((i * S_ + j) * B_ + b) * 2;
    f32x2_t o = { acc0 + b2[0], acc1 + b2[1] };
    *(f32x2_t*)(out + idx) = o;
}

// Fallback if ws is unusable: recompute ha/hb tiles per block. Correctness-only.
__global__ __launch_bounds__(256) void fused_fallback(
    const float* __restrict__ emb,
    const float* __restrict__ embc,
    const float* __restrict__ W1,
    const float* __restrict__ b1,
    const float* __restrict__ W2,
    const float* __restrict__ b2,
    float* __restrict__ out)
{
    __shared__ float ha_s[16 * 132];
    __shared__ float hb_s[16 * 132];

    const int t  = threadIdx.x;
    const int i0 = blockIdx.x * 16;
    const int j0 = blockIdx.y * 16;
    const int b  = blockIdx.z;

    for (int o = t; o < 4096; o += 256) {
        const int side = o >> 11;
        const int mi   = (o >> 7) & 15;
        const int h    = o & 127;
        const int srow = ((side ? j0 : i0) + mi) * B_ + b;
        const float* x = (side ? embc : emb) + srow * D_;
        const float* w = W1 + h * (2 * D_) + side * D_;
        float s = side ? 0.f : b1[h];
        for (int d = 0; d < D_; d += 4) {
            f32x4_t xv = *(const f32x4_t*)(x + d);
            f32x4_t wv = *(const f32x4_t*)(w + d);
            s = fmaf(xv[0], wv[0], s);
            s = fmaf(xv[1], wv[1], s);
            s = fmaf(xv[2], wv[2], s);
            s = fmaf(xv[3], wv[3], s);
        }
        (side ? hb_s : ha_s)[mi * 132 + h] = s;
    }
    __syncthreads();

    const int ti = t >> 4, tj = t & 15;
    const float* pa = &ha_s[ti * 132];
    const float* pb = &hb_s[tj * 132];
    float acc0 = 0.f, acc1 = 0.f;
    #pragma unroll
    for (int h = 0; h < HID_; h += 4) {
        f32x4_t av = *(const f32x4_t*)(pa + h);
        f32x4_t bv = *(const f32x4_t*)(pb + h);
        f32x4_t w0 = *(const f32x4_t*)(W2 + h);
        f32x4_t w1 = *(const f32x4_t*)(W2 + HID_ + h);
        #pragma unroll
        for (int q = 0; q < 4; ++q) {
            float v = fmaxf(av[q] + bv[q], 0.f);
            acc0 = fmaf(v, w0[q], acc0);
            acc1 = fmaf(v, w1[q], acc1);
        }
    }
    const int i = i0 + ti, j = j0 + tj;
    const int idx = ((i * S_ + j) * B_ + b) * 2;
    f32x2_t ov = { acc0 + b2[0], acc1 + b2[1] };
    *(f32x2_t*)(out + idx) = ov;
}

extern "C" void kernel_launch(void* const* d_in, const int* in_sizes, int n_in,
                              void* d_out, int out_size, void* d_ws, size_t ws_size,
                              hipStream_t stream) {
    const float* emb  = (const float*)d_in[0];
    // d_in[1] = umask (unused), d_in[2] = qmask (unused)
    const float* embc = (const float*)d_in[3];
    const float* W1   = (const float*)d_in[4];
    const float* b1   = (const float*)d_in[5];
    const float* W2   = (const float*)d_in[6];
    const float* b2   = (const float*)d_in[7];
    float* out = (float*)d_out;

    const size_t need = (size_t)KC_ * CHF_ * sizeof(float);  // 6.29 MB
    if (d_ws != nullptr && ws_size >= need) {
        float* ws = (float*)d_ws;   // ws[kc][z][m][h]
        stage1_mfma<<<dim3(48, 2, KC_), 256, 0, stream>>>(emb, embc, W1, b1, ws);
        stage2<<<dim3(6, 6, 16), 256, 0, stream>>>(ws, W2, b2, out);
    } else {
        fused_fallback<<<dim3(6, 6, 16), 256, 0, stream>>>(emb, embc, W1, b1, W2, b2, out);
    }
}